// Round 3
// baseline (225888.550 us; speedup 1.0000x reference)
//
#include <hip/hip_runtime.h>
#include <stdint.h>

#define SS 64
#define BB 64
#define TT 100
#define HOPC 256
#define NFC 256
#define GCC 256
#define ICC 512

// fp64 transposed-weight arena offsets (in doubles)
#define OFF_FW     0
#define OFF_FWGLU  8192
#define OFF_G1IH   12288
#define OFF_G1HH   36864
#define OFF_GLU1   49152
#define OFF_G2IH   53248
#define OFF_G2HH   77824
#define OFF_GLU2   90112
#define OFF_G3IH   94208
#define OFF_G3HH   118784
#define OFF_GLU3   131072
#define OFF_SKIPD  135168
#define OFF_SKIPG  176128
#define OFF_OUT    192512
#define W_TOTAL    200704
#define XALL_DBL   (TT * BB * HOPC)   // 1,638,400 doubles

// ---------------- threefry2x32 core (verified vs Random123 KAT) ----------------
__device__ __forceinline__ uint32_t rotl32(uint32_t x, int r) {
    return (x << r) | (x >> (32 - r));
}

__device__ __forceinline__ void tf2x32(uint32_t k0, uint32_t k1, uint32_t c0, uint32_t c1,
                                       uint32_t& o0, uint32_t& o1) {
    uint32_t k2 = k0 ^ k1 ^ 0x1BD11BDAu;
    uint32_t x0 = c0 + k0, x1 = c1 + k1;
    x0 += x1; x1 = rotl32(x1, 13); x1 ^= x0;
    x0 += x1; x1 = rotl32(x1, 15); x1 ^= x0;
    x0 += x1; x1 = rotl32(x1, 26); x1 ^= x0;
    x0 += x1; x1 = rotl32(x1, 6);  x1 ^= x0;
    x0 += k1; x1 += k2 + 1u;
    x0 += x1; x1 = rotl32(x1, 17); x1 ^= x0;
    x0 += x1; x1 = rotl32(x1, 29); x1 ^= x0;
    x0 += x1; x1 = rotl32(x1, 16); x1 ^= x0;
    x0 += x1; x1 = rotl32(x1, 24); x1 ^= x0;
    x0 += k2; x1 += k0 + 2u;
    x0 += x1; x1 = rotl32(x1, 13); x1 ^= x0;
    x0 += x1; x1 = rotl32(x1, 15); x1 ^= x0;
    x0 += x1; x1 = rotl32(x1, 26); x1 ^= x0;
    x0 += x1; x1 = rotl32(x1, 6);  x1 ^= x0;
    x0 += k0; x1 += k1 + 3u;
    x0 += x1; x1 = rotl32(x1, 17); x1 ^= x0;
    x0 += x1; x1 = rotl32(x1, 29); x1 ^= x0;
    x0 += x1; x1 = rotl32(x1, 16); x1 ^= x0;
    x0 += x1; x1 = rotl32(x1, 24); x1 ^= x0;
    x0 += k1; x1 += k2 + 4u;
    x0 += x1; x1 = rotl32(x1, 13); x1 ^= x0;
    x0 += x1; x1 = rotl32(x1, 15); x1 ^= x0;
    x0 += x1; x1 = rotl32(x1, 26); x1 ^= x0;
    x0 += x1; x1 = rotl32(x1, 6);  x1 ^= x0;
    x0 += k2; x1 += k0 + 5u;
    o0 = x0; o1 = x1;
}

__device__ __forceinline__ float bits_to_unif(uint32_t bits) {
    return __uint_as_float((bits >> 9) | 0x3f800000u) - 1.0f;
}

// ---- jax_threefry_partitionable=True (jax >= 0.5 default) semantics ----
// random_bits(key, 32, shape): element m -> block counter (0, m), bits = x0 ^ x1
__device__ __forceinline__ float unifP(uint32_t k0, uint32_t k1, uint32_t m) {
    uint32_t o0, o1;
    tf2x32(k0, k1, 0u, m, o0, o1);
    return bits_to_unif(o0 ^ o1);
}

__device__ __forceinline__ double noised(double v, uint32_t k0, uint32_t k1, uint32_t m) {
    float u = unifP(k0, k1, m);
    double d = v + ((double)u - 0.5) * (1.0 / 127.0);
    return fmin(1.0, fmax(-1.0, d));
}

__device__ __forceinline__ double sigmd(double v) { return 1.0 / (1.0 + exp(-v)); }

// ---------------- column-major (transposed) fp64 dot helpers ----------------
template<int R>
__device__ __forceinline__ double cd1(const double* __restrict__ wt,
                                      const double* __restrict__ x, int r) {
    double a0 = 0, a1 = 0, a2 = 0, a3 = 0;
#pragma unroll
    for (int k = 0; k < 64; k += 4) {
        a0 += wt[(k    ) * R + r] * x[k];
        a1 += wt[(k + 1) * R + r] * x[k + 1];
        a2 += wt[(k + 2) * R + r] * x[k + 2];
        a3 += wt[(k + 3) * R + r] * x[k + 3];
    }
    return (a0 + a1) + (a2 + a3);
}

template<int R>
__device__ __forceinline__ void cd2(const double* __restrict__ wt,
                                    const double* __restrict__ x, int r,
                                    double& y0, double& y1) {
    double a0 = 0, a1 = 0, b0 = 0, b1 = 0;
#pragma unroll
    for (int k = 0; k < 64; k += 2) {
        double x0 = x[k], x1 = x[k + 1];
        const double* c0 = wt + k * R + r;
        const double* c1 = c0 + R;
        a0 += c0[0]  * x0;  b0 += c1[0]  * x1;
        a1 += c0[64] * x0;  b1 += c1[64] * x1;
    }
    y0 += a0 + b0; y1 += a1 + b1;
}

template<int R>
__device__ __forceinline__ void cd3(const double* __restrict__ wt,
                                    const double* __restrict__ x, int r,
                                    double& y0, double& y1, double& y2) {
    double a0 = 0, a1 = 0, a2 = 0, b0 = 0, b1 = 0, b2 = 0;
#pragma unroll
    for (int k = 0; k < 64; k += 2) {
        double x0 = x[k], x1 = x[k + 1];
        const double* c0 = wt + k * R + r;
        const double* c1 = c0 + R;
        a0 += c0[0]   * x0;  b0 += c1[0]   * x1;
        a1 += c0[64]  * x0;  b1 += c1[64]  * x1;
        a2 += c0[128] * x0;  b2 += c1[128] * x1;
    }
    y0 += a0 + b0; y1 += a1 + b1; y2 += a2 + b2;
}

// ---------------- weight convert + transpose to fp64 ----------------
struct SrcW { const float* p[14]; };

__global__ __launch_bounds__(256) void fargan_cvtw(SrcW s, double* __restrict__ dst) {
    const int offs[15] = {0, 8192, 12288, 36864, 49152, 53248, 77824, 90112,
                          94208, 118784, 131072, 135168, 176128, 192512, 200704};
    const int Rs[14] = {64, 64, 192, 192, 64, 192, 192, 64, 192, 192, 64, 128, 128, 64};
    const int Ks[14] = {128, 64, 128, 64, 64, 128, 64, 64, 128, 64, 64, 320, 128, 128};
    int i = blockIdx.x * 256 + threadIdx.x;
    if (i >= W_TOTAL) return;
    int sgi = 0;
#pragma unroll
    for (int t = 1; t < 14; ++t) sgi += (i >= offs[t]);
    int j = i - offs[sgi];
    int K = Ks[sgi], R = Rs[sgi];
    int r = j / K;
    int k = j - r * K;
    dst[offs[sgi] + k * R + r] = (double)s.p[sgi][j];   // row-major -> col-major
}

// ---------------- frame input network (fp64) ----------------
__global__ __launch_bounds__(256) void fargan_frame(
    const float* __restrict__ features, const float* __restrict__ gfeat,
    const float* __restrict__ W1, const float* __restrict__ ib1,
    const float* __restrict__ W2, const float* __restrict__ ib2,
    double* __restrict__ xall)
{
    __shared__ __align__(16) double cat[8][ICC];
    __shared__ __align__(16) double zb[8][ICC];
    const int tid = threadIdx.x;
    const int t = blockIdx.x >> 3;
    const int q = blockIdx.x & 7;

    for (int bb = 0; bb < 8; ++bb) {
        int b = q * 8 + bb;
        for (int c = tid; c < ICC; c += 256) {
            float v = (c < NFC) ? features[b * NFC * TT + c * TT + t]
                                : gfeat[b * GCC + (c - NFC)];
            cat[bb][c] = (double)v;
        }
    }
    __syncthreads();

    {
        int rg = tid & 63, bg = tid >> 6;
        int n0 = rg * 8, bb0 = bg * 2;
        double acc[8][2];
#pragma unroll
        for (int r = 0; r < 8; ++r) { acc[r][0] = 0.0; acc[r][1] = 0.0; }
        for (int k = 0; k < ICC; k += 4) {
            double c00 = cat[bb0][k],     c01 = cat[bb0][k + 1];
            double c02 = cat[bb0][k + 2], c03 = cat[bb0][k + 3];
            double c10 = cat[bb0 + 1][k],     c11 = cat[bb0 + 1][k + 1];
            double c12 = cat[bb0 + 1][k + 2], c13 = cat[bb0 + 1][k + 3];
#pragma unroll
            for (int r = 0; r < 8; ++r) {
                float4 wv = *(const float4*)&W1[(n0 + r) * ICC + k];
                double w0 = wv.x, w1 = wv.y, w2 = wv.z, w3 = wv.w;
                acc[r][0] += w0 * c00 + w1 * c01 + w2 * c02 + w3 * c03;
                acc[r][1] += w0 * c10 + w1 * c11 + w2 * c12 + w3 * c13;
            }
        }
#pragma unroll
        for (int r = 0; r < 8; ++r) {
            double bias = (double)ib1[n0 + r];
            zb[bb0][n0 + r]     = tanh(acc[r][0] + bias);
            zb[bb0 + 1][n0 + r] = tanh(acc[r][1] + bias);
        }
    }
    __syncthreads();

    {
        int rg = tid & 63, bg = tid >> 6;
        int n0 = rg * 4, bb0 = bg * 2;
        double acc[4][2];
#pragma unroll
        for (int r = 0; r < 4; ++r) { acc[r][0] = 0.0; acc[r][1] = 0.0; }
        for (int k = 0; k < ICC; k += 4) {
            double c00 = zb[bb0][k],     c01 = zb[bb0][k + 1];
            double c02 = zb[bb0][k + 2], c03 = zb[bb0][k + 3];
            double c10 = zb[bb0 + 1][k],     c11 = zb[bb0 + 1][k + 1];
            double c12 = zb[bb0 + 1][k + 2], c13 = zb[bb0 + 1][k + 3];
#pragma unroll
            for (int r = 0; r < 4; ++r) {
                float4 wv = *(const float4*)&W2[(n0 + r) * ICC + k];
                double w0 = wv.x, w1 = wv.y, w2 = wv.z, w3 = wv.w;
                acc[r][0] += w0 * c00 + w1 * c01 + w2 * c02 + w3 * c03;
                acc[r][1] += w0 * c10 + w1 * c11 + w2 * c12 + w3 * c13;
            }
        }
#pragma unroll
        for (int r = 0; r < 4; ++r) {
            double bias = (double)ib2[n0 + r];
            int b0 = q * 8 + bb0;
            xall[(t * BB + b0) * HOPC + n0 + r]       = acc[r][0] + bias;
            xall[(t * BB + b0 + 1) * HOPC + n0 + r]   = acc[r][1] + bias;
        }
    }
}

// ---------------- sequential subframe chain (fp64) ----------------
// 64 blocks (one per batch element) x 64 threads (single wave)
__global__ __launch_bounds__(64) void fargan_seq(
    const double* __restrict__ xall, const double* __restrict__ wd,
    float* __restrict__ outp)
{
    const int tid = threadIdx.x;
    const int b = blockIdx.x;

    __shared__ __align__(16) double xsub[64], prevN[64], s3[64], h1s[64], h2s[64], h3s[64];
    __shared__ __align__(16) double fw[64], g1v[64], g2v[64], g3v[64], tw[64], hN[64], prevOut[64];
    __shared__ __align__(16) double spN[128], skipv[128];
    __shared__ uint32_t kkb[20];   // kk[j] = (kkb[2j], kkb[2j+1]) — foldlike split

    s3[tid] = 0.0; h1s[tid] = 0.0; h2s[tid] = 0.0; h3s[tid] = 0.0; prevOut[tid] = 0.0;
    if (tid < 10) {
        uint32_t f0, f1; tf2x32(0u, 1u, 0u, 0u, f0, f1);        // fold_in(key(1), 0)
        uint32_t A, Bv;  tf2x32(f0, f1, 0u, (uint32_t)tid, A, Bv);  // foldlike split: kk[j]=block(0,j)
        kkb[2 * tid] = A; kkb[2 * tid + 1] = Bv;
    }
    __syncthreads();

    const double* wfw   = wd + OFF_FW;
    const double* wfwg  = wd + OFF_FWGLU;
    const double* wskd  = wd + OFF_SKIPD;
    const double* wskg  = wd + OFF_SKIPG;
    const double* wout  = wd + OFF_OUT;

    for (int t = 0; t < TT; ++t) {
        for (int s = 0; s < 4; ++s) {
            const int idx = t * 4 + s;
            const uint32_t m64 = (uint32_t)(b * 64 + tid);

            // N1: noise(sub), noise(prev)
            {
                double xv = xall[(t * BB + b) * HOPC + s * SS + tid];
                xsub[tid]  = noised(xv, kkb[0], kkb[1], m64);
                prevN[tid] = noised(prevOut[tid], kkb[2], kkb[3], m64);
            }
            __syncthreads();
            // FW1: tw = tanh(fw_W @ [xsub, s3])
            tw[tid] = tanh(cd1<64>(wfw, xsub, tid) + cd1<64>(wfw + 64 * 64, s3, tid));
            __syncthreads();
            // FW2: fw = noise(tw * sigm(fw_glu @ tw)); s3 <- xsub
            {
                double gate = cd1<64>(wfwg, tw, tid);
                fw[tid] = noised(tw[tid] * sigmd(gate), kkb[4], kkb[5], m64);
                s3[tid] = xsub[tid];
            }
            __syncthreads();

#define GRU_GLU(WIH, WHH, GLUW, IN0, H, KH0, KH1, KG0, KG1, GDST)                          \
            {                                                                               \
                double ir = 0, iz = 0, inn = 0;                                             \
                cd3<192>(wd + WIH, IN0, tid, ir, iz, inn);                                  \
                cd3<192>(wd + WIH + 64 * 192, prevN, tid, ir, iz, inn);                     \
                double hr = 0, hz = 0, hn = 0;                                              \
                cd3<192>(wd + WHH, H, tid, hr, hz, hn);                                     \
                double hold = H[tid];                                                       \
                double r  = sigmd(ir + hr);                                                 \
                double z  = sigmd(iz + hz);                                                 \
                double nn = tanh(inn + r * hn);                                             \
                double hnew = (1.0 - z) * nn + z * hold;                                    \
                __syncthreads();                                                            \
                H[tid] = hnew;                                                              \
                hN[tid] = noised(hnew, KH0, KH1, m64);                                      \
                __syncthreads();                                                            \
                double gate = cd1<64>(wd + GLUW, hN, tid);                                  \
                GDST[tid] = noised(hN[tid] * sigmd(gate), KG0, KG1, m64);                   \
            }                                                                               \
            __syncthreads();

            GRU_GLU(OFF_G1IH, OFF_G1HH, OFF_GLU1, fw,  h1s, kkb[6],  kkb[7],  kkb[8],  kkb[9],  g1v)
            GRU_GLU(OFF_G2IH, OFF_G2HH, OFF_GLU2, g1v, h2s, kkb[10], kkb[11], kkb[12], kkb[13], g2v)
            GRU_GLU(OFF_G3IH, OFF_G3HH, OFF_GLU3, g2v, h3s, kkb[14], kkb[15], kkb[16], kkb[17], g3v)
#undef GRU_GLU

            // S1: spN = noise(tanh(skip_dense @ [g1,g2,g3,fw,prevN]))   (B,128)
            {
                double s0 = 0, s1 = 0;
                cd2<128>(wskd,              g1v,   tid, s0, s1);
                cd2<128>(wskd +  64 * 128,  g2v,   tid, s0, s1);
                cd2<128>(wskd + 128 * 128,  g3v,   tid, s0, s1);
                cd2<128>(wskd + 192 * 128,  fw,    tid, s0, s1);
                cd2<128>(wskd + 256 * 128,  prevN, tid, s0, s1);
                spN[tid]      = noised(tanh(s0), kkb[18], kkb[19], (uint32_t)(b * 128 + tid));
                spN[tid + 64] = noised(tanh(s1), kkb[18], kkb[19], (uint32_t)(b * 128 + tid + 64));
            }
            __syncthreads();
            // S2: skip = spN * sigm(skip_glu @ spN)
            {
                double t0 = 0, t1 = 0;
                cd2<128>(wskg,            spN,      tid, t0, t1);
                cd2<128>(wskg + 64 * 128, spN + 64, tid, t0, t1);
                skipv[tid]      = spN[tid]      * sigmd(t0);
                skipv[tid + 64] = spN[tid + 64] * sigmd(t1);
            }
            __syncthreads();
            // OUT
            {
                double o = tanh(cd1<64>(wout, skipv, tid) + cd1<64>(wout + 64 * 64, skipv + 64, tid));
                prevOut[tid] = o;
                outp[b * (TT * HOPC) + t * HOPC + s * SS + tid] = (float)o;
                if (tid < 10 && idx + 1 < 400) {
                    uint32_t f0, f1; tf2x32(0u, 1u, 0u, (uint32_t)(idx + 1), f0, f1);
                    uint32_t A, Bv;  tf2x32(f0, f1, 0u, (uint32_t)tid, A, Bv);
                    kkb[2 * tid] = A; kkb[2 * tid + 1] = Bv;
                }
            }
            __syncthreads();
        }
    }
}

extern "C" void kernel_launch(void* const* d_in, const int* in_sizes, int n_in,
                              void* d_out, int out_size, void* d_ws, size_t ws_size,
                              hipStream_t stream) {
    const float* features = (const float*)d_in[0];
    const float* gfeat    = (const float*)d_in[1];
    const float* W1       = (const float*)d_in[2];
    const float* ib1      = (const float*)d_in[3];
    const float* W2       = (const float*)d_in[4];
    const float* ib2      = (const float*)d_in[5];

    double* xall  = (double*)d_ws;                 // 13.1 MB
    double* wbase = xall + XALL_DBL;               // 1.6 MB
    float*  outp  = (float*)d_out;

    SrcW sw;
    for (int i = 0; i < 14; ++i) sw.p[i] = (const float*)d_in[6 + i];

    hipLaunchKernelGGL(fargan_cvtw, dim3((W_TOTAL + 255) / 256), dim3(256), 0, stream, sw, wbase);
    hipLaunchKernelGGL(fargan_frame, dim3(TT * 8), dim3(256), 0, stream,
                       features, gfeat, W1, ib1, W2, ib2, xall);
    hipLaunchKernelGGL(fargan_seq, dim3(BB), dim3(64), 0, stream, xall, wbase, outp);
}

// Round 4
// 33448.318 us; speedup vs baseline: 6.7534x; 6.7534x over previous
//
#include <hip/hip_runtime.h>
#include <stdint.h>

#define SS 64
#define BB 64
#define TT 100
#define HOPC 256
#define NFC 256
#define GCC 256
#define ICC 512
#define NC (1.0f/127.0f)
#define NB 8          // chains per block
#define NBLK 8        // blocks
#define NTHR 512      // 8 waves

// ---------------- threefry2x32 core (Random123-KAT verified) ----------------
__device__ __forceinline__ uint32_t rotl32(uint32_t x, int r) {
    return (x << r) | (x >> (32 - r));
}

__device__ __forceinline__ void tf2x32(uint32_t k0, uint32_t k1, uint32_t c0, uint32_t c1,
                                       uint32_t& o0, uint32_t& o1) {
    uint32_t k2 = k0 ^ k1 ^ 0x1BD11BDAu;
    uint32_t x0 = c0 + k0, x1 = c1 + k1;
    x0 += x1; x1 = rotl32(x1, 13); x1 ^= x0;
    x0 += x1; x1 = rotl32(x1, 15); x1 ^= x0;
    x0 += x1; x1 = rotl32(x1, 26); x1 ^= x0;
    x0 += x1; x1 = rotl32(x1, 6);  x1 ^= x0;
    x0 += k1; x1 += k2 + 1u;
    x0 += x1; x1 = rotl32(x1, 17); x1 ^= x0;
    x0 += x1; x1 = rotl32(x1, 29); x1 ^= x0;
    x0 += x1; x1 = rotl32(x1, 16); x1 ^= x0;
    x0 += x1; x1 = rotl32(x1, 24); x1 ^= x0;
    x0 += k2; x1 += k0 + 2u;
    x0 += x1; x1 = rotl32(x1, 13); x1 ^= x0;
    x0 += x1; x1 = rotl32(x1, 15); x1 ^= x0;
    x0 += x1; x1 = rotl32(x1, 26); x1 ^= x0;
    x0 += x1; x1 = rotl32(x1, 6);  x1 ^= x0;
    x0 += k0; x1 += k1 + 3u;
    x0 += x1; x1 = rotl32(x1, 17); x1 ^= x0;
    x0 += x1; x1 = rotl32(x1, 29); x1 ^= x0;
    x0 += x1; x1 = rotl32(x1, 16); x1 ^= x0;
    x0 += x1; x1 = rotl32(x1, 24); x1 ^= x0;
    x0 += k1; x1 += k2 + 4u;
    x0 += x1; x1 = rotl32(x1, 13); x1 ^= x0;
    x0 += x1; x1 = rotl32(x1, 15); x1 ^= x0;
    x0 += x1; x1 = rotl32(x1, 26); x1 ^= x0;
    x0 += x1; x1 = rotl32(x1, 6);  x1 ^= x0;
    x0 += k2; x1 += k0 + 5u;
    o0 = x0; o1 = x1;
}

// jax_threefry_partitionable semantics: bits(m) = x0^x1 of block (0, m)
__device__ __forceinline__ float unifP(uint32_t k0, uint32_t k1, uint32_t m) {
    uint32_t o0, o1;
    tf2x32(k0, k1, 0u, m, o0, o1);
    uint32_t bits = o0 ^ o1;
    return __uint_as_float((bits >> 9) | 0x3f800000u) - 1.0f;
}

__device__ __forceinline__ float clipf(float v) { return fminf(1.0f, fmaxf(-1.0f, v)); }
__device__ __forceinline__ float noisef(float v, uint32_t k0, uint32_t k1, uint32_t m) {
    return clipf(v + (unifP(k0, k1, m) - 0.5f) * NC);
}
__device__ __forceinline__ float sigmf(float v) { return 1.0f / (1.0f + __expf(-v)); }

// ---------------- panel matvec: Y[row+64j][c] += sum_k W[row+64j][k] X[c][k] ---
// 512 lanes: row = tid>>3 (64), g = tid&7 (k-group of 8). acc accumulates.
template<int NR, int KL, int WST, int XST>
__device__ __forceinline__ void panelK(const float* __restrict__ W,
                                       const float* __restrict__ Xl,
                                       float (&acc)[NR][8], int row, int g) {
    constexpr int Kg = KL / 8;
    const int k0 = g * Kg;
#pragma unroll
    for (int kk = 0; kk < Kg; kk += 4) {
        const int kb = k0 + kk;
        float4 xv[8];
#pragma unroll
        for (int c = 0; c < 8; ++c)
            xv[c] = *(const float4*)&Xl[c * XST + kb];
#pragma unroll
        for (int j = 0; j < NR; ++j) {
            float4 w = *(const float4*)&W[(row + 64 * j) * WST + kb];
#pragma unroll
            for (int c = 0; c < 8; ++c)
                acc[j][c] += w.x * xv[c].x + w.y * xv[c].y + w.z * xv[c].z + w.w * xv[c].w;
        }
    }
}

template<int NR>
__device__ __forceinline__ void reduce8(float (&acc)[NR][8]) {
#pragma unroll
    for (int j = 0; j < NR; ++j)
#pragma unroll
        for (int c = 0; c < 8; ++c) {
            float v = acc[j][c];
            v += __shfl_xor(v, 1);
            v += __shfl_xor(v, 2);
            v += __shfl_xor(v, 4);
            acc[j][c] = v;
        }
}

// ---------------- frame input network (fp32) ----------------
__global__ __launch_bounds__(256) void fargan_frame(
    const float* __restrict__ features, const float* __restrict__ gfeat,
    const float* __restrict__ W1, const float* __restrict__ ib1,
    const float* __restrict__ W2, const float* __restrict__ ib2,
    float* __restrict__ xall)
{
    __shared__ __align__(16) float cat[16][ICC];
    __shared__ __align__(16) float zb[16][ICC];
    const int tid = threadIdx.x;
    const int t = blockIdx.x >> 2;
    const int q = blockIdx.x & 3;

    for (int bb = 0; bb < 16; ++bb) {
        int b = q * 16 + bb;
        for (int c = tid; c < ICC; c += 256) {
            float v = (c < NFC) ? features[b * NFC * TT + c * TT + t]
                                : gfeat[b * GCC + (c - NFC)];
            cat[bb][c] = v;
        }
    }
    __syncthreads();

    {
        int rg = tid & 63, bg = tid >> 6;
        int n0 = rg * 8, bb0 = bg * 4;
        float acc[8][4];
#pragma unroll
        for (int r = 0; r < 8; ++r)
#pragma unroll
            for (int j = 0; j < 4; ++j) acc[r][j] = 0.f;
        for (int k = 0; k < ICC; k += 4) {
            float4 cv[4];
#pragma unroll
            for (int j = 0; j < 4; ++j) cv[j] = *(const float4*)&cat[bb0 + j][k];
#pragma unroll
            for (int r = 0; r < 8; ++r) {
                float4 wv = *(const float4*)&W1[(n0 + r) * ICC + k];
#pragma unroll
                for (int j = 0; j < 4; ++j)
                    acc[r][j] += wv.x * cv[j].x + wv.y * cv[j].y + wv.z * cv[j].z + wv.w * cv[j].w;
            }
        }
#pragma unroll
        for (int r = 0; r < 8; ++r) {
            float bias = ib1[n0 + r];
#pragma unroll
            for (int j = 0; j < 4; ++j)
                zb[bb0 + j][n0 + r] = tanhf(acc[r][j] + bias);
        }
    }
    __syncthreads();

    {
        int rg = tid & 63, bg = tid >> 6;
        int n0 = rg * 4, bb0 = bg * 4;
        float acc[4][4];
#pragma unroll
        for (int r = 0; r < 4; ++r)
#pragma unroll
            for (int j = 0; j < 4; ++j) acc[r][j] = 0.f;
        for (int k = 0; k < ICC; k += 4) {
            float4 cv[4];
#pragma unroll
            for (int j = 0; j < 4; ++j) cv[j] = *(const float4*)&zb[bb0 + j][k];
#pragma unroll
            for (int r = 0; r < 4; ++r) {
                float4 wv = *(const float4*)&W2[(n0 + r) * ICC + k];
#pragma unroll
                for (int j = 0; j < 4; ++j)
                    acc[r][j] += wv.x * cv[j].x + wv.y * cv[j].y + wv.z * cv[j].z + wv.w * cv[j].w;
            }
        }
#pragma unroll
        for (int r = 0; r < 4; ++r) {
            float bias = ib2[n0 + r];
#pragma unroll
            for (int j = 0; j < 4; ++j) {
                int b = q * 16 + bb0 + j;
                xall[(t * BB + b) * HOPC + n0 + r] = acc[r][j] + bias;
            }
        }
    }
}

// ---------------- sequential chain: 8 blocks x 512 threads, 8 chains/block ----
__global__ __launch_bounds__(512, 2) void fargan_seq(
    const float* __restrict__ xall,
    const float* __restrict__ fw_W, const float* __restrict__ fw_glu_W,
    const float* __restrict__ g1_Wih, const float* __restrict__ g1_Whh, const float* __restrict__ glu1_W,
    const float* __restrict__ g2_Wih, const float* __restrict__ g2_Whh, const float* __restrict__ glu2_W,
    const float* __restrict__ g3_Wih, const float* __restrict__ g3_Whh, const float* __restrict__ glu3_W,
    const float* __restrict__ skipd_W, const float* __restrict__ skipg_W, const float* __restrict__ out_W,
    float* __restrict__ outp)
{
    const int tid = threadIdx.x;
    const int row = tid >> 3;
    const int g = tid & 7;
    const int bg = blockIdx.x * NB + g;       // this lane's chain for elementwise ops

    // LDS activation buffers, [chain][k] layout, padded strides (16B-aligned)
    __shared__ __align__(16) float SKX[8 * 324];   // g1|g2|g3|fw|prevN  (K=320 + pad 4)
    __shared__ __align__(16) float XS [8 * 132];   // xsub|s3            (K=128 + pad 4)
    __shared__ __align__(16) float H1 [8 * 68], H2[8 * 68], H3[8 * 68];
    __shared__ __align__(16) float TW [8 * 68];
    __shared__ __align__(16) float HN [8 * 68];
    __shared__ __align__(16) float SPN[8 * 132];
    __shared__ __align__(16) float SKV[8 * 132];
    __shared__ __align__(16) float PO [8 * 68];
    __shared__ uint32_t kkb[20];               // kk[j] = (kkb[2j], kkb[2j+1])

    // init state
    H1[g * 68 + row] = 0.f; H2[g * 68 + row] = 0.f; H3[g * 68 + row] = 0.f;
    PO[g * 68 + row] = 0.f;
    XS[g * 132 + row] = 0.f; XS[g * 132 + 64 + row] = 0.f;
    if (tid < 10) {
        uint32_t f0, f1; tf2x32(0u, 1u, 0u, 0u, f0, f1);          // fold_in(key(1), 0)
        uint32_t A, Bv;  tf2x32(f0, f1, 0u, (uint32_t)tid, A, Bv); // foldlike split
        kkb[2 * tid] = A; kkb[2 * tid + 1] = Bv;
    }
    __syncthreads();

    for (int t = 0; t < TT; ++t) {
        for (int s = 0; s < 4; ++s) {
            const int idx = t * 4 + s;
            const uint32_t m64 = (uint32_t)(bg * 64 + row);

            // ---- E0: s3 <- old xsub; xsub = noise(x); prevN = noise(prevOut)
            {
                float xo = XS[g * 132 + row];
                float xv = xall[(t * BB + bg) * HOPC + s * SS + row];
                XS[g * 132 + 64 + row] = xo;                                 // s3
                XS[g * 132 + row] = noisef(xv, kkb[0], kkb[1], m64);         // xsub
                float po = PO[g * 68 + row];
                SKX[g * 324 + 256 + row] = noisef(po, kkb[2], kkb[3], m64);  // prevN
            }
            __syncthreads();

            // ---- FW1: tw = tanh(fw_W @ [xsub; s3])
            float twv;
            {
                float a[1][8] = {{0}};
                panelK<1, 128, 128, 132>(fw_W, XS, a, row, g);
                reduce8(a);
                twv = tanhf(a[0][g]);
                TW[g * 68 + row] = twv;
            }
            __syncthreads();

            // ---- FW2: fw = noise(tw * sigm(fw_glu @ tw))
            {
                float a[1][8] = {{0}};
                panelK<1, 64, 64, 68>(fw_glu_W, TW, a, row, g);
                reduce8(a);
                SKX[g * 324 + 192 + row] = noisef(twv * sigmf(a[0][g]), kkb[4], kkb[5], m64);
            }
            __syncthreads();

            // ---- GRU + GLU x3
#define GRU_GLU(PH1, PH2, WHH, GLUW, HBUF, KH, KG, GOFF)                                   \
            {                                                                               \
                float ai[3][8] = {{0}};                                                     \
                PH1; PH2;                                                                   \
                float ah[3][8] = {{0}};                                                     \
                panelK<3, 64, 64, 68>(WHH, HBUF, ah, row, g);                               \
                reduce8(ai); reduce8(ah);                                                   \
                float hold = HBUF[g * 68 + row];                                            \
                float r  = sigmf(ai[0][g] + ah[0][g]);                                      \
                float z  = sigmf(ai[1][g] + ah[1][g]);                                      \
                float nn = tanhf(ai[2][g] + r * ah[2][g]);                                  \
                float hnew = (1.f - z) * nn + z * hold;                                     \
                float hN = noisef(hnew, kkb[KH], kkb[KH + 1], m64);                         \
                __syncthreads();                                                            \
                HBUF[g * 68 + row] = hnew;                                                  \
                HN[g * 68 + row] = hN;                                                      \
                __syncthreads();                                                            \
                float ag[1][8] = {{0}};                                                     \
                panelK<1, 64, 64, 68>(GLUW, HN, ag, row, g);                                \
                reduce8(ag);                                                                \
                SKX[g * 324 + GOFF + row] =                                                 \
                    noisef(hN * sigmf(ag[0][g]), kkb[KG], kkb[KG + 1], m64);                \
            }                                                                               \
            __syncthreads();

            GRU_GLU((panelK<3,128,128,324>(g1_Wih, SKX + 192, ai, row, g)), ,
                    g1_Whh, glu1_W, H1, 6, 8, 0)
            GRU_GLU((panelK<3,64,128,324>(g2_Wih, SKX, ai, row, g)),
                    (panelK<3,64,128,324>(g2_Wih + 64, SKX + 256, ai, row, g)),
                    g2_Whh, glu2_W, H2, 10, 12, 64)
            GRU_GLU((panelK<3,64,128,324>(g3_Wih, SKX + 64, ai, row, g)),
                    (panelK<3,64,128,324>(g3_Wih + 64, SKX + 256, ai, row, g)),
                    g3_Whh, glu3_W, H3, 14, 16, 128)
#undef GRU_GLU

            // ---- SKIP: spN = noise(tanh(skip_dense @ SKX[0:320]))
            float sp0, sp1;
            {
                float a[2][8] = {{0}};
                panelK<2, 320, 320, 324>(skipd_W, SKX, a, row, g);
                reduce8(a);
                uint32_t mb = (uint32_t)(bg * 128 + row);
                sp0 = noisef(tanhf(a[0][g]), kkb[18], kkb[19], mb);
                sp1 = noisef(tanhf(a[1][g]), kkb[18], kkb[19], mb + 64u);
                SPN[g * 132 + row] = sp0;
                SPN[g * 132 + 64 + row] = sp1;
            }
            __syncthreads();

            // ---- SG: skip = spN * sigm(skip_glu @ spN)
            {
                float a[2][8] = {{0}};
                panelK<2, 128, 128, 132>(skipg_W, SPN, a, row, g);
                reduce8(a);
                SKV[g * 132 + row] = sp0 * sigmf(a[0][g]);
                SKV[g * 132 + 64 + row] = sp1 * sigmf(a[1][g]);
            }
            __syncthreads();

            // ---- OUT: o = tanh(out_W @ skip)
            {
                float a[1][8] = {{0}};
                panelK<1, 128, 128, 132>(out_W, SKV, a, row, g);
                reduce8(a);
                float o = tanhf(a[0][g]);
                PO[g * 68 + row] = o;
                outp[bg * (TT * HOPC) + t * HOPC + s * SS + row] = o;
                if (tid < 10 && idx + 1 < 400) {
                    uint32_t f0, f1; tf2x32(0u, 1u, 0u, (uint32_t)(idx + 1), f0, f1);
                    uint32_t A, Bv;  tf2x32(f0, f1, 0u, (uint32_t)tid, A, Bv);
                    kkb[2 * tid] = A; kkb[2 * tid + 1] = Bv;
                }
            }
            __syncthreads();
        }
    }
}

extern "C" void kernel_launch(void* const* d_in, const int* in_sizes, int n_in,
                              void* d_out, int out_size, void* d_ws, size_t ws_size,
                              hipStream_t stream) {
    const float* features = (const float*)d_in[0];
    const float* gfeat    = (const float*)d_in[1];
    const float* W1       = (const float*)d_in[2];
    const float* ib1      = (const float*)d_in[3];
    const float* W2       = (const float*)d_in[4];
    const float* ib2      = (const float*)d_in[5];

    float* xall = (float*)d_ws;     // 6.55 MB
    float* outp = (float*)d_out;

    hipLaunchKernelGGL(fargan_frame, dim3(TT * 4), dim3(256), 0, stream,
                       features, gfeat, W1, ib1, W2, ib2, xall);
    hipLaunchKernelGGL(fargan_seq, dim3(NBLK), dim3(NTHR), 0, stream,
                       xall,
                       (const float*)d_in[6], (const float*)d_in[7],
                       (const float*)d_in[8], (const float*)d_in[9], (const float*)d_in[10],
                       (const float*)d_in[11], (const float*)d_in[12], (const float*)d_in[13],
                       (const float*)d_in[14], (const float*)d_in[15], (const float*)d_in[16],
                       (const float*)d_in[17], (const float*)d_in[18], (const float*)d_in[19],
                       outp);
}

// Round 5
// 7501.056 us; speedup vs baseline: 30.1142x; 4.4591x over previous
//
#include <hip/hip_runtime.h>
#include <stdint.h>

#define SS 64
#define BB 64
#define TT 100
#define HOPC 256
#define NFC 256
#define GCC 256
#define ICC 512
#define NC (1.0f/127.0f)
#define NBLK 64       // one block per chain
#define NTHR 512      // 8 waves: lane = (row, g), row=tid>>3, g=tid&7

// ---------------- threefry2x32 core (Random123-KAT verified) ----------------
__device__ __forceinline__ uint32_t rotl32(uint32_t x, int r) {
    return (x << r) | (x >> (32 - r));
}

__device__ __forceinline__ void tf2x32(uint32_t k0, uint32_t k1, uint32_t c0, uint32_t c1,
                                       uint32_t& o0, uint32_t& o1) {
    uint32_t k2 = k0 ^ k1 ^ 0x1BD11BDAu;
    uint32_t x0 = c0 + k0, x1 = c1 + k1;
    x0 += x1; x1 = rotl32(x1, 13); x1 ^= x0;
    x0 += x1; x1 = rotl32(x1, 15); x1 ^= x0;
    x0 += x1; x1 = rotl32(x1, 26); x1 ^= x0;
    x0 += x1; x1 = rotl32(x1, 6);  x1 ^= x0;
    x0 += k1; x1 += k2 + 1u;
    x0 += x1; x1 = rotl32(x1, 17); x1 ^= x0;
    x0 += x1; x1 = rotl32(x1, 29); x1 ^= x0;
    x0 += x1; x1 = rotl32(x1, 16); x1 ^= x0;
    x0 += x1; x1 = rotl32(x1, 24); x1 ^= x0;
    x0 += k2; x1 += k0 + 2u;
    x0 += x1; x1 = rotl32(x1, 13); x1 ^= x0;
    x0 += x1; x1 = rotl32(x1, 15); x1 ^= x0;
    x0 += x1; x1 = rotl32(x1, 26); x1 ^= x0;
    x0 += x1; x1 = rotl32(x1, 6);  x1 ^= x0;
    x0 += k0; x1 += k1 + 3u;
    x0 += x1; x1 = rotl32(x1, 17); x1 ^= x0;
    x0 += x1; x1 = rotl32(x1, 29); x1 ^= x0;
    x0 += x1; x1 = rotl32(x1, 16); x1 ^= x0;
    x0 += x1; x1 = rotl32(x1, 24); x1 ^= x0;
    x0 += k1; x1 += k2 + 4u;
    x0 += x1; x1 = rotl32(x1, 13); x1 ^= x0;
    x0 += x1; x1 = rotl32(x1, 15); x1 ^= x0;
    x0 += x1; x1 = rotl32(x1, 26); x1 ^= x0;
    x0 += x1; x1 = rotl32(x1, 6);  x1 ^= x0;
    x0 += k2; x1 += k0 + 5u;
    o0 = x0; o1 = x1;
}

// jax_threefry_partitionable semantics: bits(m) = x0^x1 of block (0, m)
__device__ __forceinline__ float unifP(uint32_t k0, uint32_t k1, uint32_t m) {
    uint32_t o0, o1;
    tf2x32(k0, k1, 0u, m, o0, o1);
    uint32_t bits = o0 ^ o1;
    return __uint_as_float((bits >> 9) | 0x3f800000u) - 1.0f;
}

__device__ __forceinline__ float clipf(float v) { return fminf(1.0f, fmaxf(-1.0f, v)); }
__device__ __forceinline__ float sigmf(float v) { return 1.0f / (1.0f + __expf(-v)); }
// noise with precomputed uniform
__device__ __forceinline__ float noiseu(float v, float u) {
    return clipf(v + (u - 0.5f) * NC);
}

// ---------------- single-chain panel matvec ----------------
// Y[row+64j] += sum_k W[row+64j][k] * X[k];  lane (row,g) covers k in [g*K/8,(g+1)*K/8)
template<int NR, int KL, int WST>
__device__ __forceinline__ void panel1(const float* __restrict__ W,
                                       const float* __restrict__ Xl,
                                       float (&acc)[NR], int row, int g) {
    constexpr int Kg = KL / 8;
    const int k0 = g * Kg;
#pragma unroll
    for (int kk = 0; kk < Kg; kk += 4) {
        const int kb = k0 + kk;
        float4 xv = *(const float4*)&Xl[kb];
#pragma unroll
        for (int j = 0; j < NR; ++j) {
            float4 w = *(const float4*)&W[(row + 64 * j) * WST + kb];
            acc[j] += w.x * xv.x + w.y * xv.y + w.z * xv.z + w.w * xv.w;
        }
    }
}

template<int NR>
__device__ __forceinline__ void red8(float (&a)[NR]) {
#pragma unroll
    for (int j = 0; j < NR; ++j) {
        float v = a[j];
        v += __shfl_xor(v, 1);
        v += __shfl_xor(v, 2);
        v += __shfl_xor(v, 4);
        a[j] = v;     // all 8 g-lanes hold the full sum
    }
}

// ---------------- frame input network (fp32) ----------------
__global__ __launch_bounds__(256) void fargan_frame(
    const float* __restrict__ features, const float* __restrict__ gfeat,
    const float* __restrict__ W1, const float* __restrict__ ib1,
    const float* __restrict__ W2, const float* __restrict__ ib2,
    float* __restrict__ xall)
{
    __shared__ __align__(16) float cat[16][ICC];
    __shared__ __align__(16) float zb[16][ICC];
    const int tid = threadIdx.x;
    const int t = blockIdx.x >> 2;
    const int q = blockIdx.x & 3;

    for (int bb = 0; bb < 16; ++bb) {
        int b = q * 16 + bb;
        for (int c = tid; c < ICC; c += 256) {
            float v = (c < NFC) ? features[b * NFC * TT + c * TT + t]
                                : gfeat[b * GCC + (c - NFC)];
            cat[bb][c] = v;
        }
    }
    __syncthreads();

    {
        int rg = tid & 63, bg = tid >> 6;
        int n0 = rg * 8, bb0 = bg * 4;
        float acc[8][4];
#pragma unroll
        for (int r = 0; r < 8; ++r)
#pragma unroll
            for (int j = 0; j < 4; ++j) acc[r][j] = 0.f;
        for (int k = 0; k < ICC; k += 4) {
            float4 cv[4];
#pragma unroll
            for (int j = 0; j < 4; ++j) cv[j] = *(const float4*)&cat[bb0 + j][k];
#pragma unroll
            for (int r = 0; r < 8; ++r) {
                float4 wv = *(const float4*)&W1[(n0 + r) * ICC + k];
#pragma unroll
                for (int j = 0; j < 4; ++j)
                    acc[r][j] += wv.x * cv[j].x + wv.y * cv[j].y + wv.z * cv[j].z + wv.w * cv[j].w;
            }
        }
#pragma unroll
        for (int r = 0; r < 8; ++r) {
            float bias = ib1[n0 + r];
#pragma unroll
            for (int j = 0; j < 4; ++j)
                zb[bb0 + j][n0 + r] = tanhf(acc[r][j] + bias);
        }
    }
    __syncthreads();

    {
        int rg = tid & 63, bg = tid >> 6;
        int n0 = rg * 4, bb0 = bg * 4;
        float acc[4][4];
#pragma unroll
        for (int r = 0; r < 4; ++r)
#pragma unroll
            for (int j = 0; j < 4; ++j) acc[r][j] = 0.f;
        for (int k = 0; k < ICC; k += 4) {
            float4 cv[4];
#pragma unroll
            for (int j = 0; j < 4; ++j) cv[j] = *(const float4*)&zb[bb0 + j][k];
#pragma unroll
            for (int r = 0; r < 4; ++r) {
                float4 wv = *(const float4*)&W2[(n0 + r) * ICC + k];
#pragma unroll
                for (int j = 0; j < 4; ++j)
                    acc[r][j] += wv.x * cv[j].x + wv.y * cv[j].y + wv.z * cv[j].z + wv.w * cv[j].w;
            }
        }
#pragma unroll
        for (int r = 0; r < 4; ++r) {
            float bias = ib2[n0 + r];
#pragma unroll
            for (int j = 0; j < 4; ++j) {
                int b = q * 16 + bb0 + j;
                xall[(t * BB + b) * HOPC + n0 + r] = acc[r][j] + bias;
            }
        }
    }
}

// ---------------- sequential chain: 64 blocks (1 chain each) x 512 threads ----
// UNF slots (per subframe, 64 each unless noted):
//  0:sub 1:prev 2:fw 3:g1-h 4:g1-glu 5:g2-h 6:g2-glu 7:g3-h 8:g3-glu 9..10: skip(128)
__global__ __launch_bounds__(512, 2) void fargan_seq(
    const float* __restrict__ xall,
    const float* __restrict__ fw_W, const float* __restrict__ fw_glu_W,
    const float* __restrict__ g1_Wih, const float* __restrict__ g1_Whh, const float* __restrict__ glu1_W,
    const float* __restrict__ g2_Wih, const float* __restrict__ g2_Whh, const float* __restrict__ glu2_W,
    const float* __restrict__ g3_Wih, const float* __restrict__ g3_Whh, const float* __restrict__ glu3_W,
    const float* __restrict__ skipd_W, const float* __restrict__ skipg_W, const float* __restrict__ out_W,
    float* __restrict__ outp)
{
    const int tid = threadIdx.x;
    const int row = tid >> 3;
    const int g = tid & 7;
    const int bg = blockIdx.x;          // chain id

    __shared__ __align__(16) float SKX[320];   // g1|g2|g3|fw|prevN
    __shared__ __align__(16) float XS[128];    // xsub|s3
    __shared__ __align__(16) float H1[64], H2[64], H3[64];
    __shared__ __align__(16) float TW[64], HN[64];
    __shared__ __align__(16) float SPN[128], SKV[128];
    __shared__ __align__(16) float UNF[704];   // precomputed uniforms for this subframe
    __shared__ uint32_t kkb[20];               // kk[j] = (kkb[2j], kkb[2j+1])

    float prevO = 0.f;
    if (g == 0) {
        H1[row] = 0.f; H2[row] = 0.f; H3[row] = 0.f;
        XS[row] = 0.f; XS[64 + row] = 0.f;
    }
    if (tid < 10) {
        uint32_t f0, f1; tf2x32(0u, 1u, 0u, 0u, f0, f1);           // fold_in(key(1), 0)
        uint32_t A, Bv;  tf2x32(f0, f1, 0u, (uint32_t)tid, A, Bv); // foldlike split
        kkb[2 * tid] = A; kkb[2 * tid + 1] = Bv;
    }
    __syncthreads();

    for (int t = 0; t < TT; ++t) {
        for (int s = 0; s < 4; ++s) {
            const int idx = t * 4 + s;

            // ---- Phase A: precompute uniforms; stage reads before overwrite
            float xo = XS[row];                                    // old xsub -> s3
            float xv = xall[(t * BB + bg) * HOPC + s * SS + row];
#pragma unroll
            for (int rep = 0; rep < 2; ++rep) {
                int j = tid + rep * 512;
                if (j < 704) {
                    int sl = j >> 6;
                    uint32_t m = (sl < 9) ? (uint32_t)(bg * 64 + (j & 63))
                                          : (uint32_t)(bg * 128 + (j - 576));
                    int kx = (sl < 9) ? 2 * sl : 18;
                    UNF[j] = unifP(kkb[kx], kkb[kx + 1], m);
                }
            }
            __syncthreads();

            // ---- Phase B: write xsub/s3/prevN
            if (g == 0) {
                XS[64 + row] = xo;
                XS[row]      = noiseu(xv, UNF[row]);
                SKX[256 + row] = noiseu(prevO, UNF[64 + row]);
            }
            __syncthreads();

            // ---- FW1: tw = tanh(fw_W @ [xsub; s3])
            float a1[1] = {0};
            panel1<1, 128, 128>(fw_W, XS, a1, row, g);
            red8(a1);
            float twv = tanhf(a1[0]);
            if (g == 0) TW[row] = twv;
            __syncthreads();

            // ---- FW2: fw = noise(tw * sigm(fw_glu @ tw))
            float a2[1] = {0};
            panel1<1, 64, 64>(fw_glu_W, TW, a2, row, g);
            red8(a2);
            if (g == 0) SKX[192 + row] = noiseu(twv * sigmf(a2[0]), UNF[128 + row]);
            __syncthreads();

            // ---- GRU + GLU x3
#define GRU_GLU(P1, P2, WHH, GLUW, HBUF, UH, UG, GOFF)                                     \
            {                                                                               \
                float ai[3] = {0, 0, 0};                                                    \
                P1; P2;                                                                     \
                float ah[3] = {0, 0, 0};                                                    \
                panel1<3, 64, 64>(WHH, HBUF, ah, row, g);                                   \
                red8(ai); red8(ah);                                                         \
                float hold = HBUF[row];                                                     \
                float r  = sigmf(ai[0] + ah[0]);                                            \
                float z  = sigmf(ai[1] + ah[1]);                                            \
                float nn = tanhf(ai[2] + r * ah[2]);                                        \
                float hnew = (1.f - z) * nn + z * hold;                                     \
                float hNv = noiseu(hnew, UNF[(UH) + row]);                                  \
                __syncthreads();                                                            \
                if (g == 0) { HBUF[row] = hnew; HN[row] = hNv; }                            \
                __syncthreads();                                                            \
                float ag[1] = {0};                                                          \
                panel1<1, 64, 64>(GLUW, HN, ag, row, g);                                    \
                red8(ag);                                                                   \
                if (g == 0) SKX[(GOFF) + row] = noiseu(hNv * sigmf(ag[0]), UNF[(UG) + row]);\
            }                                                                               \
            __syncthreads();

            GRU_GLU((panel1<3, 128, 128>(g1_Wih, SKX + 192, ai, row, g)), ,
                    g1_Whh, glu1_W, H1, 192, 256, 0)
            GRU_GLU((panel1<3, 64, 128>(g2_Wih, SKX, ai, row, g)),
                    (panel1<3, 64, 128>(g2_Wih + 64, SKX + 256, ai, row, g)),
                    g2_Whh, glu2_W, H2, 320, 384, 64)
            GRU_GLU((panel1<3, 64, 128>(g3_Wih, SKX + 64, ai, row, g)),
                    (panel1<3, 64, 128>(g3_Wih + 64, SKX + 256, ai, row, g)),
                    g3_Whh, glu3_W, H3, 448, 512, 128)
#undef GRU_GLU

            // ---- SKIP: spN = noise(tanh(skip_dense @ SKX[0:320]))
            float as[2] = {0, 0};
            panel1<2, 320, 320>(skipd_W, SKX, as, row, g);
            red8(as);
            float sp0 = noiseu(tanhf(as[0]), UNF[576 + row]);
            float sp1 = noiseu(tanhf(as[1]), UNF[576 + 64 + row]);
            if (g == 0) { SPN[row] = sp0; SPN[64 + row] = sp1; }
            __syncthreads();

            // ---- SG: skip = spN * sigm(skip_glu @ spN)
            float ag2[2] = {0, 0};
            panel1<2, 128, 128>(skipg_W, SPN, ag2, row, g);
            red8(ag2);
            if (g == 0) { SKV[row] = sp0 * sigmf(ag2[0]); SKV[64 + row] = sp1 * sigmf(ag2[1]); }
            __syncthreads();

            // ---- OUT: o = tanh(out_W @ skip); update keys for next subframe
            float ao[1] = {0};
            panel1<1, 128, 128>(out_W, SKV, ao, row, g);
            red8(ao);
            float o = tanhf(ao[0]);
            prevO = o;
            if (g == 0) outp[bg * (TT * HOPC) + t * HOPC + s * SS + row] = o;
            if (tid < 10 && idx + 1 < 400) {
                uint32_t f0, f1; tf2x32(0u, 1u, 0u, (uint32_t)(idx + 1), f0, f1);
                uint32_t A, Bv;  tf2x32(f0, f1, 0u, (uint32_t)tid, A, Bv);
                kkb[2 * tid] = A; kkb[2 * tid + 1] = Bv;
            }
            __syncthreads();
        }
    }
}

extern "C" void kernel_launch(void* const* d_in, const int* in_sizes, int n_in,
                              void* d_out, int out_size, void* d_ws, size_t ws_size,
                              hipStream_t stream) {
    const float* features = (const float*)d_in[0];
    const float* gfeat    = (const float*)d_in[1];
    const float* W1       = (const float*)d_in[2];
    const float* ib1      = (const float*)d_in[3];
    const float* W2       = (const float*)d_in[4];
    const float* ib2      = (const float*)d_in[5];

    float* xall = (float*)d_ws;     // 6.55 MB
    float* outp = (float*)d_out;

    hipLaunchKernelGGL(fargan_frame, dim3(TT * 4), dim3(256), 0, stream,
                       features, gfeat, W1, ib1, W2, ib2, xall);
    hipLaunchKernelGGL(fargan_seq, dim3(NBLK), dim3(NTHR), 0, stream,
                       xall,
                       (const float*)d_in[6], (const float*)d_in[7],
                       (const float*)d_in[8], (const float*)d_in[9], (const float*)d_in[10],
                       (const float*)d_in[11], (const float*)d_in[12], (const float*)d_in[13],
                       (const float*)d_in[14], (const float*)d_in[15], (const float*)d_in[16],
                       (const float*)d_in[17], (const float*)d_in[18], (const float*)d_in[19],
                       outp);
}

// Round 6
// 3234.629 us; speedup vs baseline: 69.8345x; 2.3190x over previous
//
#include <hip/hip_runtime.h>
#include <stdint.h>

#define SS 64
#define BB 64
#define TT 100
#define HOPC 256
#define NFC 256
#define GCC 256
#define ICC 512
#define NC (1.0f/127.0f)
#define NBLK 64       // one block per chain
#define NTHR 512      // 8 waves: lane = (row, g), row=tid>>3, g=tid&7

// f16 weight arena offsets (in halves; same order as inputs 6..19)
#define OFF_FW     0
#define OFF_FWGLU  8192
#define OFF_G1IH   12288
#define OFF_G1HH   36864
#define OFF_GLU1   49152
#define OFF_G2IH   53248
#define OFF_G2HH   77824
#define OFF_GLU2   90112
#define OFF_G3IH   94208
#define OFF_G3HH   118784
#define OFF_GLU3   131072
#define OFF_SKIPD  135168
#define OFF_SKIPG  176128
#define OFF_OUT    192512
#define W_TOTAL    200704
#define XALL_F32   (TT * BB * HOPC)   // 1,638,400 floats

typedef _Float16 f16;
typedef _Float16 h2 __attribute__((ext_vector_type(2)));
union U16 { uint4 u; h2 h[4]; };

#if __has_builtin(__builtin_amdgcn_fdot2)
#define FDOT2(a, b, c) __builtin_amdgcn_fdot2((a), (b), (c), false)
#else
#define FDOT2(a, b, c) ((c) + (float)(a)[0] * (float)(b)[0] + (float)(a)[1] * (float)(b)[1])
#endif

// ---------------- threefry2x32 core (Random123-KAT verified) ----------------
__device__ __forceinline__ uint32_t rotl32(uint32_t x, int r) {
    return (x << r) | (x >> (32 - r));
}

__device__ __forceinline__ void tf2x32(uint32_t k0, uint32_t k1, uint32_t c0, uint32_t c1,
                                       uint32_t& o0, uint32_t& o1) {
    uint32_t k2 = k0 ^ k1 ^ 0x1BD11BDAu;
    uint32_t x0 = c0 + k0, x1 = c1 + k1;
    x0 += x1; x1 = rotl32(x1, 13); x1 ^= x0;
    x0 += x1; x1 = rotl32(x1, 15); x1 ^= x0;
    x0 += x1; x1 = rotl32(x1, 26); x1 ^= x0;
    x0 += x1; x1 = rotl32(x1, 6);  x1 ^= x0;
    x0 += k1; x1 += k2 + 1u;
    x0 += x1; x1 = rotl32(x1, 17); x1 ^= x0;
    x0 += x1; x1 = rotl32(x1, 29); x1 ^= x0;
    x0 += x1; x1 = rotl32(x1, 16); x1 ^= x0;
    x0 += x1; x1 = rotl32(x1, 24); x1 ^= x0;
    x0 += k2; x1 += k0 + 2u;
    x0 += x1; x1 = rotl32(x1, 13); x1 ^= x0;
    x0 += x1; x1 = rotl32(x1, 15); x1 ^= x0;
    x0 += x1; x1 = rotl32(x1, 26); x1 ^= x0;
    x0 += x1; x1 = rotl32(x1, 6);  x1 ^= x0;
    x0 += k0; x1 += k1 + 3u;
    x0 += x1; x1 = rotl32(x1, 17); x1 ^= x0;
    x0 += x1; x1 = rotl32(x1, 29); x1 ^= x0;
    x0 += x1; x1 = rotl32(x1, 16); x1 ^= x0;
    x0 += x1; x1 = rotl32(x1, 24); x1 ^= x0;
    x0 += k1; x1 += k2 + 4u;
    x0 += x1; x1 = rotl32(x1, 13); x1 ^= x0;
    x0 += x1; x1 = rotl32(x1, 15); x1 ^= x0;
    x0 += x1; x1 = rotl32(x1, 26); x1 ^= x0;
    x0 += x1; x1 = rotl32(x1, 6);  x1 ^= x0;
    x0 += k2; x1 += k0 + 5u;
    o0 = x0; o1 = x1;
}

// jax_threefry_partitionable semantics: bits(m) = x0^x1 of block (0, m)
__device__ __forceinline__ float unifP(uint32_t k0, uint32_t k1, uint32_t m) {
    uint32_t o0, o1;
    tf2x32(k0, k1, 0u, m, o0, o1);
    uint32_t bits = o0 ^ o1;
    return __uint_as_float((bits >> 9) | 0x3f800000u) - 1.0f;
}

__device__ __forceinline__ float clipf(float v) { return fminf(1.0f, fmaxf(-1.0f, v)); }
__device__ __forceinline__ float sigmf(float v) { return 1.0f / (1.0f + __expf(-v)); }
__device__ __forceinline__ float noiseu(float v, float u) {
    return clipf(v + (u - 0.5f) * NC);
}

// ---------------- f16 dot helpers (fp32 accumulate via v_dot2) ----------------
// 16-half dot: w = U16[2]; x = LDS halves (16B aligned)
__device__ __forceinline__ float dotK16(const U16* w, const f16* x, float acc) {
    U16 xa, xb;
    xa.u = *(const uint4*)x;
    xb.u = *(const uint4*)(x + 8);
#pragma unroll
    for (int i = 0; i < 4; ++i) acc = FDOT2(w[0].h[i], xa.h[i], acc);
#pragma unroll
    for (int i = 0; i < 4; ++i) acc = FDOT2(w[1].h[i], xb.h[i], acc);
    return acc;
}
// 8-half dot
__device__ __forceinline__ float dotK8(const U16& w, const f16* x, float acc) {
    U16 xa;
    xa.u = *(const uint4*)x;
#pragma unroll
    for (int i = 0; i < 4; ++i) acc = FDOT2(w.h[i], xa.h[i], acc);
    return acc;
}

template<int NR>
__device__ __forceinline__ void red8(float (&a)[NR]) {
#pragma unroll
    for (int j = 0; j < NR; ++j) {
        float v = a[j];
        v += __shfl_xor(v, 1);
        v += __shfl_xor(v, 2);
        v += __shfl_xor(v, 4);
        a[j] = v;
    }
}

// ---------------- phase weight register structs + loaders ----------------
struct WF1  { U16 w[2]; };                        // K=128, NR=1
struct WGRU { U16 wih[6]; U16 whh[3]; U16 glu; }; // Wih K=128 NR=3, Whh K=64 NR=3, glu K=64
struct WSK  { U16 w[10]; };                       // K=320, NR=2
struct WSG  { U16 w[4]; };                        // K=128, NR=2

__device__ __forceinline__ void ldF1(const f16* W, int row, int g, WF1& r) {
    const f16* p = W + row * 128 + g * 16;
    r.w[0].u = *(const uint4*)p;
    r.w[1].u = *(const uint4*)(p + 8);
}
__device__ __forceinline__ void ldF2(const f16* W, int row, int g, U16& r) {
    r.u = *(const uint4*)(W + row * 64 + g * 8);
}
__device__ __forceinline__ void ldGRU(const f16* Wih, const f16* Whh, const f16* Glu,
                                      int row, int g, WGRU& r) {
#pragma unroll
    for (int j = 0; j < 3; ++j) {
        const f16* p = Wih + (row + 64 * j) * 128 + g * 16;
        r.wih[2 * j].u     = *(const uint4*)p;
        r.wih[2 * j + 1].u = *(const uint4*)(p + 8);
        r.whh[j].u = *(const uint4*)(Whh + (row + 64 * j) * 64 + g * 8);
    }
    r.glu.u = *(const uint4*)(Glu + row * 64 + g * 8);
}
__device__ __forceinline__ void ldSK(const f16* W, int row, int g, WSK& r) {
#pragma unroll
    for (int j = 0; j < 2; ++j) {
        const f16* p = W + (row + 64 * j) * 320 + g * 40;
#pragma unroll
        for (int i = 0; i < 5; ++i) r.w[5 * j + i].u = *(const uint4*)(p + 8 * i);
    }
}
__device__ __forceinline__ void ldSG(const f16* W, int row, int g, WSG& r) {
#pragma unroll
    for (int j = 0; j < 2; ++j) {
        const f16* p = W + (row + 64 * j) * 128 + g * 16;
        r.w[2 * j].u     = *(const uint4*)p;
        r.w[2 * j + 1].u = *(const uint4*)(p + 8);
    }
}

// ---------------- weight convert to f16 (flat, same layout) ----------------
struct SrcW { const float* p[14]; };

__global__ __launch_bounds__(256) void fargan_cvtw(SrcW s, f16* __restrict__ dst) {
    const int offs[15] = {0, 8192, 12288, 36864, 49152, 53248, 77824, 90112,
                          94208, 118784, 131072, 135168, 176128, 192512, 200704};
    int i = blockIdx.x * 256 + threadIdx.x;
    if (i >= W_TOTAL) return;
    int sgi = 0;
#pragma unroll
    for (int t = 1; t < 14; ++t) sgi += (i >= offs[t]);
    dst[i] = (f16)s.p[sgi][i - offs[sgi]];
}

// ---------------- frame input network (fp32) ----------------
__global__ __launch_bounds__(256) void fargan_frame(
    const float* __restrict__ features, const float* __restrict__ gfeat,
    const float* __restrict__ W1, const float* __restrict__ ib1,
    const float* __restrict__ W2, const float* __restrict__ ib2,
    float* __restrict__ xall)
{
    __shared__ __align__(16) float cat[16][ICC];
    __shared__ __align__(16) float zb[16][ICC];
    const int tid = threadIdx.x;
    const int t = blockIdx.x >> 2;
    const int q = blockIdx.x & 3;

    for (int bb = 0; bb < 16; ++bb) {
        int b = q * 16 + bb;
        for (int c = tid; c < ICC; c += 256) {
            float v = (c < NFC) ? features[b * NFC * TT + c * TT + t]
                                : gfeat[b * GCC + (c - NFC)];
            cat[bb][c] = v;
        }
    }
    __syncthreads();

    {
        int rg = tid & 63, bg = tid >> 6;
        int n0 = rg * 8, bb0 = bg * 4;
        float acc[8][4];
#pragma unroll
        for (int r = 0; r < 8; ++r)
#pragma unroll
            for (int j = 0; j < 4; ++j) acc[r][j] = 0.f;
        for (int k = 0; k < ICC; k += 4) {
            float4 cv[4];
#pragma unroll
            for (int j = 0; j < 4; ++j) cv[j] = *(const float4*)&cat[bb0 + j][k];
#pragma unroll
            for (int r = 0; r < 8; ++r) {
                float4 wv = *(const float4*)&W1[(n0 + r) * ICC + k];
#pragma unroll
                for (int j = 0; j < 4; ++j)
                    acc[r][j] += wv.x * cv[j].x + wv.y * cv[j].y + wv.z * cv[j].z + wv.w * cv[j].w;
            }
        }
#pragma unroll
        for (int r = 0; r < 8; ++r) {
            float bias = ib1[n0 + r];
#pragma unroll
            for (int j = 0; j < 4; ++j)
                zb[bb0 + j][n0 + r] = tanhf(acc[r][j] + bias);
        }
    }
    __syncthreads();

    {
        int rg = tid & 63, bg = tid >> 6;
        int n0 = rg * 4, bb0 = bg * 4;
        float acc[4][4];
#pragma unroll
        for (int r = 0; r < 4; ++r)
#pragma unroll
            for (int j = 0; j < 4; ++j) acc[r][j] = 0.f;
        for (int k = 0; k < ICC; k += 4) {
            float4 cv[4];
#pragma unroll
            for (int j = 0; j < 4; ++j) cv[j] = *(const float4*)&zb[bb0 + j][k];
#pragma unroll
            for (int r = 0; r < 4; ++r) {
                float4 wv = *(const float4*)&W2[(n0 + r) * ICC + k];
#pragma unroll
                for (int j = 0; j < 4; ++j)
                    acc[r][j] += wv.x * cv[j].x + wv.y * cv[j].y + wv.z * cv[j].z + wv.w * cv[j].w;
            }
        }
#pragma unroll
        for (int r = 0; r < 4; ++r) {
            float bias = ib2[n0 + r];
#pragma unroll
            for (int j = 0; j < 4; ++j) {
                int b = q * 16 + bb0 + j;
                xall[(t * BB + b) * HOPC + n0 + r] = acc[r][j] + bias;
            }
        }
    }
}

// ---------------- sequential chain: 64 blocks x 512 threads, f16 + prefetch --
__global__ __launch_bounds__(512, 2) void fargan_seq(
    const float* __restrict__ xall, const f16* __restrict__ wh,
    float* __restrict__ outp)
{
    const int tid = threadIdx.x;
    const int row = tid >> 3;
    const int g = tid & 7;
    const int bg = blockIdx.x;          // chain id

    // fp32 state
    __shared__ __align__(16) float XS[128];               // xsub|s3 (delay line)
    __shared__ __align__(16) float H1[64], H2[64], H3[64];
    __shared__ __align__(16) float UNF[704];
    // f16 matvec operand mirrors
    __shared__ __align__(16) f16 XH[128];                 // xsub|s3
    __shared__ __align__(16) f16 SKXH[320];               // g1|g2|g3|fw|prevN
    __shared__ __align__(16) f16 H1H[64], H2H[64], H3H[64];
    __shared__ __align__(16) f16 TWH[64], HNH[64];
    __shared__ __align__(16) f16 SPNH[128], SKVH[128];
    __shared__ uint32_t kkb[20];        // kk[j] = (kkb[2j], kkb[2j+1])

    const f16* whFW  = wh + OFF_FW;
    const f16* whFWG = wh + OFF_FWGLU;

    float prevO = 0.f;
    if (g == 0) {
        H1[row] = 0.f; H2[row] = 0.f; H3[row] = 0.f;
        H1H[row] = (f16)0.f; H2H[row] = (f16)0.f; H3H[row] = (f16)0.f;
        XS[row] = 0.f; XS[64 + row] = 0.f;
        XH[row] = (f16)0.f; XH[64 + row] = (f16)0.f;
    }
    if (tid < 10) {
        uint32_t f0, f1; tf2x32(0u, 1u, 0u, 0u, f0, f1);           // fold_in(key(1), 0)
        uint32_t A, Bv;  tf2x32(f0, f1, 0u, (uint32_t)tid, A, Bv); // foldlike split
        kkb[2 * tid] = A; kkb[2 * tid + 1] = Bv;
    }
    __syncthreads();

    // pipeline registers
    WF1 rF1; U16 rF2; WGRU rGa, rGb; WSK rSK; WSG rSG; WF1 rOUT;

    ldF1(whFW, row, g, rF1);            // preload FW1

    for (int t = 0; t < TT; ++t) {
        for (int s = 0; s < 4; ++s) {
            const int idx = t * 4 + s;

            // ---- A: prefetch FW2; stage reads; precompute all uniforms
            ldF2(whFWG, row, g, rF2);
            float xo = XS[row];
            float xv = xall[(t * BB + bg) * HOPC + s * SS + row];
#pragma unroll
            for (int rep = 0; rep < 2; ++rep) {
                int j = tid + rep * 512;
                if (j < 704) {
                    int sl = j >> 6;
                    uint32_t m = (sl < 9) ? (uint32_t)(bg * 64 + (j & 63))
                                          : (uint32_t)(bg * 128 + (j - 576));
                    int kx = (sl < 9) ? 2 * sl : 18;
                    UNF[j] = unifP(kkb[kx], kkb[kx + 1], m);
                }
            }
            __syncthreads();

            // ---- B: write xsub/s3/prevN (state + f16 mirrors)
            if (g == 0) {
                XS[64 + row] = xo;           XH[64 + row] = (f16)xo;
                float xs = noiseu(xv, UNF[row]);
                XS[row] = xs;                XH[row] = (f16)xs;
                SKXH[256 + row] = (f16)noiseu(prevO, UNF[64 + row]);
            }
            __syncthreads();

            // ---- FW1: prefetch G1; tw = tanh(fw_W @ [xsub; s3])
            ldGRU(wh + OFF_G1IH, wh + OFF_G1HH, wh + OFF_GLU1, row, g, rGa);
            float a1[1] = {0};
            a1[0] = dotK16(rF1.w, XH + g * 16, a1[0]);
            red8<1>(a1);
            float twv = tanhf(a1[0]);
            if (g == 0) TWH[row] = (f16)twv;
            __syncthreads();

            // ---- FW2: prefetch G2; fw = noise(tw * sigm(fw_glu @ tw))
            ldGRU(wh + OFF_G2IH, wh + OFF_G2HH, wh + OFF_GLU2, row, g, rGb);
            float a2[1] = {0};
            a2[0] = dotK8(rF2, TWH + g * 8, a2[0]);
            red8<1>(a2);
            if (g == 0) SKXH[192 + row] = (f16)noiseu(twv * sigmf(a2[0]), UNF[128 + row]);
            __syncthreads();

            // ---- GRU + GLU x3 (prefetch embedded at call sites)
#define GRU_GLU(RG, XIN, HBUF, HH, UH, UG, GOFF)                                           \
            {                                                                               \
                float ai[3] = {0, 0, 0};                                                    \
                const f16* xin = (XIN);                                                     \
                _Pragma("unroll")                                                           \
                for (int j = 0; j < 3; ++j) ai[j] = dotK16(&RG.wih[2 * j], xin, ai[j]);     \
                float ah[3] = {0, 0, 0};                                                    \
                const f16* xh = HH + g * 8;                                                 \
                _Pragma("unroll")                                                           \
                for (int j = 0; j < 3; ++j) ah[j] = dotK8(RG.whh[j], xh, ah[j]);            \
                red8<3>(ai); red8<3>(ah);                                                   \
                float hold = HBUF[row];                                                     \
                float r  = sigmf(ai[0] + ah[0]);                                            \
                float z  = sigmf(ai[1] + ah[1]);                                            \
                float nn = tanhf(ai[2] + r * ah[2]);                                        \
                float hnew = (1.f - z) * nn + z * hold;                                     \
                float hNv = noiseu(hnew, UNF[(UH) + row]);                                  \
                __syncthreads();                                                            \
                if (g == 0) { HBUF[row] = hnew; HH[row] = (f16)hnew; HNH[row] = (f16)hNv; } \
                __syncthreads();                                                            \
                float ag[1] = {0};                                                          \
                ag[0] = dotK8(RG.glu, HNH + g * 8, ag[0]);                                  \
                red8<1>(ag);                                                                \
                if (g == 0) SKXH[(GOFF) + row] =                                            \
                    (f16)noiseu(hNv * sigmf(ag[0]), UNF[(UG) + row]);                       \
            }                                                                               \
            __syncthreads();

            // G1 (input [fw|prevN] = SKXH+192, contiguous)
            GRU_GLU(rGa, SKXH + 192 + g * 16, H1, H1H, 192, 256, 0)
            // G2: prefetch G3 into rGa (free); input [g1|prevN] split
            ldGRU(wh + OFF_G3IH, wh + OFF_G3HH, wh + OFF_GLU3, row, g, rGa);
            GRU_GLU(rGb, (g < 4 ? SKXH + g * 16 : SKXH + 256 + (g - 4) * 16), H2, H2H, 320, 384, 64)
            // G3: prefetch SKIP; input [g2|prevN] split
            ldSK(wh + OFF_SKIPD, row, g, rSK);
            GRU_GLU(rGa, (g < 4 ? SKXH + 64 + g * 16 : SKXH + 256 + (g - 4) * 16), H3, H3H, 448, 512, 128)
#undef GRU_GLU

            // ---- SKIP: prefetch SG; spN = noise(tanh(skip_dense @ SKXH[0:320]))
            ldSG(wh + OFF_SKIPG, row, g, rSG);
            float as[2] = {0, 0};
            {
                const f16* xs = SKXH + g * 40;
#pragma unroll
                for (int j = 0; j < 2; ++j)
#pragma unroll
                    for (int i = 0; i < 5; ++i)
                        as[j] = dotK8(rSK.w[5 * j + i], xs + 8 * i, as[j]);
            }
            red8<2>(as);
            float sp0 = noiseu(tanhf(as[0]), UNF[576 + row]);
            float sp1 = noiseu(tanhf(as[1]), UNF[640 + row]);
            if (g == 0) { SPNH[row] = (f16)sp0; SPNH[64 + row] = (f16)sp1; }
            __syncthreads();

            // ---- SG: prefetch OUT; skip = spN * sigm(skip_glu @ spN)
            ldF1(wh + OFF_OUT, row, g, rOUT);
            float ag2[2] = {0, 0};
            {
                const f16* xg = SPNH + g * 16;
#pragma unroll
                for (int j = 0; j < 2; ++j) {
                    ag2[j] = dotK8(rSG.w[2 * j], xg, ag2[j]);
                    ag2[j] = dotK8(rSG.w[2 * j + 1], xg + 8, ag2[j]);
                }
            }
            red8<2>(ag2);
            if (g == 0) {
                SKVH[row]      = (f16)(sp0 * sigmf(ag2[0]));
                SKVH[64 + row] = (f16)(sp1 * sigmf(ag2[1]));
            }
            __syncthreads();

            // ---- OUT: prefetch next FW1; o = tanh(out_W @ skip); keys
            ldF1(whFW, row, g, rF1);
            float ao[1] = {0};
            ao[0] = dotK16(rOUT.w, SKVH + g * 16, ao[0]);
            red8<1>(ao);
            float o = tanhf(ao[0]);
            prevO = o;
            if (g == 0) outp[bg * (TT * HOPC) + t * HOPC + s * SS + row] = o;
            if (tid < 10 && idx + 1 < 400) {
                uint32_t f0, f1; tf2x32(0u, 1u, 0u, (uint32_t)(idx + 1), f0, f1);
                uint32_t A, Bv;  tf2x32(f0, f1, 0u, (uint32_t)tid, A, Bv);
                kkb[2 * tid] = A; kkb[2 * tid + 1] = Bv;
            }
            __syncthreads();
        }
    }
}

extern "C" void kernel_launch(void* const* d_in, const int* in_sizes, int n_in,
                              void* d_out, int out_size, void* d_ws, size_t ws_size,
                              hipStream_t stream) {
    const float* features = (const float*)d_in[0];
    const float* gfeat    = (const float*)d_in[1];
    const float* W1       = (const float*)d_in[2];
    const float* ib1      = (const float*)d_in[3];
    const float* W2       = (const float*)d_in[4];
    const float* ib2      = (const float*)d_in[5];

    float* xall = (float*)d_ws;                    // 6.55 MB
    f16*   wh   = (f16*)(xall + XALL_F32);         // 0.40 MB, 16B-aligned
    float* outp = (float*)d_out;

    SrcW sw;
    for (int i = 0; i < 14; ++i) sw.p[i] = (const float*)d_in[6 + i];

    hipLaunchKernelGGL(fargan_cvtw, dim3((W_TOTAL + 255) / 256), dim3(256), 0, stream, sw, wh);
    hipLaunchKernelGGL(fargan_frame, dim3(TT * 4), dim3(256), 0, stream,
                       features, gfeat, W1, ib1, W2, ib2, xall);
    hipLaunchKernelGGL(fargan_seq, dim3(NBLK), dim3(NTHR), 0, stream, xall, wh, outp);
}